// Round 1
// 257.345 us; speedup vs baseline: 1.0456x; 1.0456x over previous
//
#include <hip/hip_runtime.h>
#include <math.h>

#define B_ 32
#define C_ 2048
#define HW_ 576          // 24*24
#define P_ 4
#define HID_ 128         // C/RED
#define J_ 8192          // C*P
#define NCHUNK_ 16       // c-chunks of 128 channels
#define CSZ_ 128         // channels per chunk

// ---------------- K1: pool (one wave per (b,c) row of 576 floats) ----------------
// 16384 blocks * 4 waves = 65536 rows. 128 float4 + 64 scalar tail, all lanes active.
__global__ void pool_kernel(const float* __restrict__ x, float* __restrict__ pooled) {
    int gwave = blockIdx.x * 4 + (threadIdx.x >> 6);   // [0, 65536)
    int lane  = threadIdx.x & 63;
    const float* xr = x + (size_t)gwave * HW_;
    const float4* xp4 = (const float4*)xr;
    float4 v0 = xp4[lane];
    float4 v1 = xp4[lane + 64];
    float s = v0.x + v0.y + v0.z + v0.w
            + v1.x + v1.y + v1.z + v1.w
            + xr[512 + lane];
    #pragma unroll
    for (int off = 32; off > 0; off >>= 1) s += __shfl_down(s, off, 64);
    if (lane == 0) pooled[gwave] = s * (1.0f / (float)HW_);
}

// ---------------- K2: fc1: hidden[b,j] = silu(pooled[b,:]·fc1_w[j,:] + b1[j]) -----------
// one wave per output (32*128 = 4096), float4 loads (8 iters * 64 lanes * 4 = 2048)
__global__ void fc1_kernel(const float* __restrict__ pooled, const float* __restrict__ fc1_w,
                           const float* __restrict__ fc1_b, float* __restrict__ hidden) {
    int o    = blockIdx.x * 4 + (threadIdx.x >> 6);    // [0, 4096)
    int lane = threadIdx.x & 63;
    int b = o >> 7;
    int j = o & 127;
    const float4* pr = (const float4*)(pooled + (size_t)b * C_);
    const float4* wr = (const float4*)(fc1_w + (size_t)j * C_);
    float s = 0.f;
    #pragma unroll
    for (int i = 0; i < 8; ++i) {
        float4 p = pr[lane + 64 * i];
        float4 w = wr[lane + 64 * i];
        s += p.x * w.x + p.y * w.y + p.z * w.z + p.w * w.w;
    }
    #pragma unroll
    for (int off = 32; off > 0; off >>= 1) s += __shfl_down(s, off, 64);
    if (lane == 0) {
        float z = s + fc1_b[j];
        hidden[o] = z / (1.0f + expf(-z));             // silu
    }
}

// ---------------- K3: fc2, b-tiled: dw[b,j] = hidden[b,:]·fc2_w[j,:] + b2[j] ------------
// 256 blocks * 32 j each; each fc2_w row is read exactly ONCE (broadcast over the 32 b's).
// hidden (16 KB) staged in LDS, padded row stride 132 keeps 16B alignment + rotates banks.
// LDS-transposed store so dw writes are float4-coalesced.
__global__ void fc2_kernel(const float* __restrict__ hidden, const float* __restrict__ fc2_w,
                           const float* __restrict__ fc2_b, float* __restrict__ dw) {
    __shared__ float h[32][132];
    __shared__ float dt[32][33];
    int tid = threadIdx.x;
    int jbase = blockIdx.x * 32;

    {   // stage hidden[32][128]
        int bb = tid >> 3, q = tid & 7;
        const float4* hb = (const float4*)(hidden + (size_t)bb * HID_);
        #pragma unroll
        for (int m = 0; m < 4; ++m) {
            float4 v = hb[q + 8 * m];
            int k = (q + 8 * m) * 4;
            h[bb][k] = v.x; h[bb][k + 1] = v.y; h[bb][k + 2] = v.z; h[bb][k + 3] = v.w;
        }
    }
    __syncthreads();

    int b  = tid & 31;
    int jl = tid >> 5;                                 // 0..7
    int j0 = jbase + jl * 4;
    const float4* W = (const float4*)(fc2_w + (size_t)j0 * HID_);
    float a0 = fc2_b[j0], a1 = fc2_b[j0 + 1], a2 = fc2_b[j0 + 2], a3 = fc2_b[j0 + 3];
    #pragma unroll 8
    for (int k4 = 0; k4 < 32; ++k4) {
        float4 hv = *(const float4*)(&h[b][k4 * 4]);
        float4 wa = W[k4], wb = W[32 + k4], wc = W[64 + k4], wd = W[96 + k4];
        a0 += hv.x * wa.x + hv.y * wa.y + hv.z * wa.z + hv.w * wa.w;
        a1 += hv.x * wb.x + hv.y * wb.y + hv.z * wb.z + hv.w * wb.w;
        a2 += hv.x * wc.x + hv.y * wc.y + hv.z * wc.z + hv.w * wc.w;
        a3 += hv.x * wd.x + hv.y * wd.y + hv.z * wd.z + hv.w * wd.w;
    }
    dt[jl * 4 + 0][b] = a0;
    dt[jl * 4 + 1][b] = a1;
    dt[jl * 4 + 2][b] = a2;
    dt[jl * 4 + 3][b] = a3;
    __syncthreads();

    int b2 = tid >> 3, q2 = tid & 7;
    float4 o;
    o.x = dt[q2 * 4 + 0][b2];
    o.y = dt[q2 * 4 + 1][b2];
    o.z = dt[q2 * 4 + 2][b2];
    o.w = dt[q2 * 4 + 3][b2];
    ((float4*)(dw + (size_t)b2 * J_ + jbase))[q2] = o;
}

// ---------------- K4: einsum partials + conv_b·dw bias partial ----------------
// grid (b=32, chunk=16); 128 channels/chunk; 576 threads in 4 groups of 144.
// 512 blocks = 2 blocks/CU (18 waves) for the L3-resident second x pass.
__global__ void einsum_kernel(const float* __restrict__ x, const float* __restrict__ conv_w,
                              const float* __restrict__ conv_b, const float* __restrict__ dw,
                              float* __restrict__ part, float* __restrict__ bias_part) {
    int b     = blockIdx.x;
    int chunk = blockIdx.y;
    int c0    = chunk * CSZ_;
    int tid   = threadIdx.x;                           // [0, 576)

    __shared__ float4 m4[CSZ_];                        // m4[c] = {cw*dw[p=0..3]}
    __shared__ float4 red[P_ * HW_];                   // 36 KB
    __shared__ float4 bsum[2];
    if (tid < CSZ_) {
        int c = c0 + tid;
        float cw = conv_w[c], cb = conv_b[c];
        const float* dr = dw + (size_t)b * J_ + c;
        float d0 = dr[0 * C_], d1 = dr[1 * C_], d2 = dr[2 * C_], d3 = dr[3 * C_];
        float4 mv; mv.x = cw * d0; mv.y = cw * d1; mv.z = cw * d2; mv.w = cw * d3;
        m4[tid] = mv;
        float4 bp; bp.x = cb * d0; bp.y = cb * d1; bp.z = cb * d2; bp.w = cb * d3;
        #pragma unroll
        for (int off = 32; off > 0; off >>= 1) {
            bp.x += __shfl_down(bp.x, off, 64);
            bp.y += __shfl_down(bp.y, off, 64);
            bp.z += __shfl_down(bp.z, off, 64);
            bp.w += __shfl_down(bp.w, off, 64);
        }
        if ((tid & 63) == 0) bsum[tid >> 6] = bp;      // waves 0,1
    }
    __syncthreads();
    if (tid == 0) {
        float4 t0 = bsum[0], t1 = bsum[1];
        float4 r; r.x = t0.x + t1.x; r.y = t0.y + t1.y; r.z = t0.z + t1.z; r.w = t0.w + t1.w;
        *(float4*)(bias_part + ((size_t)(b * NCHUNK_ + chunk)) * 4) = r;
    }

    int g = tid / 144;                                 // 0..3
    int i = tid - g * 144;                             // 0..143 (float4 index in hw)

    float4 a0 = {0,0,0,0}, a1 = {0,0,0,0}, a2 = {0,0,0,0}, a3 = {0,0,0,0};
    const float* xb = x + ((size_t)b * C_ + c0) * HW_;
    #pragma unroll 4
    for (int k = 0; k < CSZ_ / 4; ++k) {
        int c = g + 4 * k;
        float4 v = ((const float4*)(xb + (size_t)c * HW_))[i];
        float4 m = m4[c];
        a0.x += v.x * m.x; a0.y += v.y * m.x; a0.z += v.z * m.x; a0.w += v.w * m.x;
        a1.x += v.x * m.y; a1.y += v.y * m.y; a1.z += v.z * m.y; a1.w += v.w * m.y;
        a2.x += v.x * m.z; a2.y += v.y * m.z; a2.z += v.z * m.z; a2.w += v.w * m.z;
        a3.x += v.x * m.w; a3.y += v.y * m.w; a3.z += v.z * m.w; a3.w += v.w * m.w;
    }
    red[0 * HW_ + tid] = a0;
    red[1 * HW_ + tid] = a1;
    red[2 * HW_ + tid] = a2;
    red[3 * HW_ + tid] = a3;
    __syncthreads();

    if (g == 0) {                                      // tid == i in [0,144)
        float4* pp = (float4*)(part + ((size_t)(b * NCHUNK_ + chunk) * P_) * HW_);
        #pragma unroll
        for (int p = 0; p < P_; ++p) {
            float4 s  = red[p * HW_ + i];
            float4 s1 = red[p * HW_ + 144 + i];
            float4 s2 = red[p * HW_ + 288 + i];
            float4 s3 = red[p * HW_ + 432 + i];
            s.x += s1.x + s2.x + s3.x;
            s.y += s1.y + s2.y + s3.y;
            s.z += s1.z + s2.z + s3.z;
            s.w += s1.w + s2.w + s3.w;
            pp[p * (HW_ / 4) + i] = s;
        }
    }
}

// ---------------- K5: reduce slots + bias + softmax over p ----------------
__global__ void softmax_kernel(const float* __restrict__ part, const float* __restrict__ bias_part,
                               float* __restrict__ out) {
    int idx = blockIdx.x * 256 + threadIdx.x;          // [0, 18432)
    int b  = idx / HW_;
    int hw = idx - b * HW_;
    const float4* bp = (const float4*)(bias_part + (size_t)b * NCHUNK_ * 4);
    float v0 = 0.f, v1 = 0.f, v2 = 0.f, v3 = 0.f;
    #pragma unroll
    for (int s = 0; s < NCHUNK_; ++s) {
        float4 t = bp[s];                              // uniform per b -> cache broadcast
        v0 += t.x; v1 += t.y; v2 += t.z; v3 += t.w;
    }
    const float* pb = part + ((size_t)b * NCHUNK_ * P_) * HW_ + hw;
    #pragma unroll
    for (int s = 0; s < NCHUNK_; ++s) {
        const float* ps = pb + (size_t)s * P_ * HW_;
        v0 += ps[0 * HW_];
        v1 += ps[1 * HW_];
        v2 += ps[2 * HW_];
        v3 += ps[3 * HW_];
    }
    float mx = fmaxf(fmaxf(v0, v1), fmaxf(v2, v3));
    float e0 = expf(v0 - mx), e1 = expf(v1 - mx), e2 = expf(v2 - mx), e3 = expf(v3 - mx);
    float inv = 1.0f / (e0 + e1 + e2 + e3);
    float* op = out + ((size_t)b * P_) * HW_ + hw;
    op[0 * HW_] = e0 * inv;
    op[1 * HW_] = e1 * inv;
    op[2 * HW_] = e2 * inv;
    op[3 * HW_] = e3 * inv;
}

extern "C" void kernel_launch(void* const* d_in, const int* in_sizes, int n_in,
                              void* d_out, int out_size, void* d_ws, size_t ws_size,
                              hipStream_t stream) {
    const float* x      = (const float*)d_in[0];
    const float* fc1_w  = (const float*)d_in[1];
    const float* fc1_b  = (const float*)d_in[2];
    const float* fc2_w  = (const float*)d_in[3];
    const float* fc2_b  = (const float*)d_in[4];
    const float* conv_w = (const float*)d_in[5];
    const float* conv_b = (const float*)d_in[6];
    float* out = (float*)d_out;

    // workspace layout (floats)
    float* ws        = (float*)d_ws;
    float* pooled    = ws;                      // 32*2048          = 65536
    float* hidden    = pooled + 65536;          // 32*128           = 4096
    float* dw        = hidden + 4096;           // 32*8192          = 262144
    float* bias_part = dw + 262144;             // 32*16*4          = 2048
    float* part      = bias_part + 2048;        // 32*16*4*576      = 1179648 (4.7 MB)

    pool_kernel<<<16384, 256, 0, stream>>>(x, pooled);
    fc1_kernel<<<1024, 256, 0, stream>>>(pooled, fc1_w, fc1_b, hidden);
    fc2_kernel<<<256, 256, 0, stream>>>(hidden, fc2_w, fc2_b, dw);
    einsum_kernel<<<dim3(B_, NCHUNK_), 576, 0, stream>>>(x, conv_w, conv_b, dw, part, bias_part);
    softmax_kernel<<<72, 256, 0, stream>>>(part, bias_part, out);
}